// Round 1
// baseline (51.318 us; speedup 1.0000x reference)
//
#include <hip/hip_runtime.h>

#define DIM 2048
#define LEN 4096
#define NB  4
#define KW  4
#define LSTRIP 16
#define COLS (DIM / 4)   // 512 float4 columns

__global__ __launch_bounds__(256) void shortconv_silu_kernel(
    const float4* __restrict__ x4,   // (B, L, D/4)
    const float*  __restrict__ w,    // (D, 1, K) flat = d*K + k
    float4* __restrict__ o4)         // (B, L, D/4)
{
    const int col = blockIdx.x * blockDim.x + threadIdx.x;  // [0, COLS)
    const int l0  = blockIdx.y * LSTRIP;
    const int b   = blockIdx.z;
    const int d0  = col * 4;

    // Load weights: wrow[i] = w[d0+i][0..3] (contiguous 16B each), then
    // transpose so wk{k}.component_i = w[d0+i][k].
    float4 wrow0 = *reinterpret_cast<const float4*>(w + (size_t)(d0 + 0) * KW);
    float4 wrow1 = *reinterpret_cast<const float4*>(w + (size_t)(d0 + 1) * KW);
    float4 wrow2 = *reinterpret_cast<const float4*>(w + (size_t)(d0 + 2) * KW);
    float4 wrow3 = *reinterpret_cast<const float4*>(w + (size_t)(d0 + 3) * KW);
    const float4 wk0 = make_float4(wrow0.x, wrow1.x, wrow2.x, wrow3.x);
    const float4 wk1 = make_float4(wrow0.y, wrow1.y, wrow2.y, wrow3.y);
    const float4 wk2 = make_float4(wrow0.z, wrow1.z, wrow2.z, wrow3.z);
    const float4 wk3 = make_float4(wrow0.w, wrow1.w, wrow2.w, wrow3.w);

    const size_t base = (size_t)b * LEN * COLS + col;
    const float4 zero = make_float4(0.f, 0.f, 0.f, 0.f);

    // Sliding window: xm3 = x[l-3], xm2 = x[l-2], xm1 = x[l-1]
    float4 xm3 = (l0 - 3 >= 0) ? x4[base + (size_t)(l0 - 3) * COLS] : zero;
    float4 xm2 = (l0 - 2 >= 0) ? x4[base + (size_t)(l0 - 2) * COLS] : zero;
    float4 xm1 = (l0 - 1 >= 0) ? x4[base + (size_t)(l0 - 1) * COLS] : zero;

    #pragma unroll
    for (int j = 0; j < LSTRIP; ++j) {
        const int l = l0 + j;
        const float4 xc = x4[base + (size_t)l * COLS];

        float4 y;
        y.x = wk0.x * xm3.x + wk1.x * xm2.x + wk2.x * xm1.x + wk3.x * xc.x;
        y.y = wk0.y * xm3.y + wk1.y * xm2.y + wk2.y * xm1.y + wk3.y * xc.y;
        y.z = wk0.z * xm3.z + wk1.z * xm2.z + wk2.z * xm1.z + wk3.z * xc.z;
        y.w = wk0.w * xm3.w + wk1.w * xm2.w + wk2.w * xm1.w + wk3.w * xc.w;

        // SiLU: y * sigmoid(y)
        y.x = y.x / (1.f + __expf(-y.x));
        y.y = y.y / (1.f + __expf(-y.y));
        y.z = y.z / (1.f + __expf(-y.z));
        y.w = y.w / (1.f + __expf(-y.w));

        o4[base + (size_t)l * COLS] = y;

        xm3 = xm2; xm2 = xm1; xm1 = xc;
    }
}

extern "C" void kernel_launch(void* const* d_in, const int* in_sizes, int n_in,
                              void* d_out, int out_size, void* d_ws, size_t ws_size,
                              hipStream_t stream) {
    const float4* x4 = (const float4*)d_in[0];
    const float*  w  = (const float*)d_in[1];
    float4* o4 = (float4*)d_out;

    dim3 block(256, 1, 1);
    dim3 grid(COLS / 256, LEN / LSTRIP, NB);  // (2, 256, 4) = 2048 blocks
    shortconv_silu_kernel<<<grid, block, 0, stream>>>(x4, w, o4);
}

// Round 2
// 48.192 us; speedup vs baseline: 1.0649x; 1.0649x over previous
//
#include <hip/hip_runtime.h>

#define DIM 2048
#define LEN 4096
#define NB  4
#define KW  4
#define LSTRIP 16
#define COLS (DIM / 4)   // 512 float4 columns

typedef float v4f __attribute__((ext_vector_type(4)));

__global__ __launch_bounds__(256) void shortconv_silu_kernel(
    const v4f* __restrict__ x4,   // (B, L, D/4)
    const float* __restrict__ w,  // (D, 1, K) flat = d*K + k
    v4f* __restrict__ o4)         // (B, L, D/4)
{
    const int col = blockIdx.x * blockDim.x + threadIdx.x;  // [0, COLS)
    const int l0  = blockIdx.y * LSTRIP;
    const int b   = blockIdx.z;
    const int d0  = col * 4;

    // Load weights: wrow[i] = w[d0+i][0..3] (contiguous 16B each), then
    // transpose so wk{k}[i] = w[d0+i][k].
    const v4f wrow0 = *reinterpret_cast<const v4f*>(w + (size_t)(d0 + 0) * KW);
    const v4f wrow1 = *reinterpret_cast<const v4f*>(w + (size_t)(d0 + 1) * KW);
    const v4f wrow2 = *reinterpret_cast<const v4f*>(w + (size_t)(d0 + 2) * KW);
    const v4f wrow3 = *reinterpret_cast<const v4f*>(w + (size_t)(d0 + 3) * KW);
    v4f wk0, wk1, wk2, wk3;
    wk0.x = wrow0.x; wk0.y = wrow1.x; wk0.z = wrow2.x; wk0.w = wrow3.x;
    wk1.x = wrow0.y; wk1.y = wrow1.y; wk1.z = wrow2.y; wk1.w = wrow3.y;
    wk2.x = wrow0.z; wk2.y = wrow1.z; wk2.z = wrow2.z; wk2.w = wrow3.z;
    wk3.x = wrow0.w; wk3.y = wrow1.w; wk3.z = wrow2.w; wk3.w = wrow3.w;

    const size_t base = (size_t)b * LEN * COLS + col;
    const v4f zero = {0.f, 0.f, 0.f, 0.f};

    // Sliding window: xm3 = x[l-3], xm2 = x[l-2], xm1 = x[l-1]
    v4f xm3 = (l0 - 3 >= 0) ? x4[base + (size_t)(l0 - 3) * COLS] : zero;
    v4f xm2 = (l0 - 2 >= 0) ? x4[base + (size_t)(l0 - 2) * COLS] : zero;
    v4f xm1 = (l0 - 1 >= 0) ? x4[base + (size_t)(l0 - 1) * COLS] : zero;

    #pragma unroll
    for (int j = 0; j < LSTRIP; ++j) {
        const int l = l0 + j;
        const v4f xc = x4[base + (size_t)l * COLS];

        v4f y = wk0 * xm3 + wk1 * xm2 + wk2 * xm1 + wk3 * xc;

        // SiLU: y * sigmoid(y)
        y.x = y.x / (1.f + __expf(-y.x));
        y.y = y.y / (1.f + __expf(-y.y));
        y.z = y.z / (1.f + __expf(-y.z));
        y.w = y.w / (1.f + __expf(-y.w));

        // Non-temporal: output is never re-read — don't evict input from L3.
        __builtin_nontemporal_store(y, o4 + base + (size_t)l * COLS);

        xm3 = xm2; xm2 = xm1; xm1 = xc;
    }
}

extern "C" void kernel_launch(void* const* d_in, const int* in_sizes, int n_in,
                              void* d_out, int out_size, void* d_ws, size_t ws_size,
                              hipStream_t stream) {
    const v4f* x4 = (const v4f*)d_in[0];
    const float* w = (const float*)d_in[1];
    v4f* o4 = (v4f*)d_out;

    dim3 block(256, 1, 1);
    dim3 grid(COLS / 256, LEN / LSTRIP, NB);  // (2, 256, 4) = 2048 blocks
    shortconv_silu_kernel<<<grid, block, 0, stream>>>(x4, w, o4);
}

// Round 3
// 47.956 us; speedup vs baseline: 1.0701x; 1.0049x over previous
//
#include <hip/hip_runtime.h>

#define DIM 2048
#define LEN 4096
#define NB  4
#define KW  4
#define LSTRIP 16
#define COLS (DIM / 4)   // 512 float4 columns

typedef float v4f __attribute__((ext_vector_type(4)));

__device__ __forceinline__ float silu1(float v) {
    // v * sigmoid(v); rcp approx is ~1ulp, far inside the 7.75e-2 threshold.
    return v * __builtin_amdgcn_rcpf(1.f + __expf(-v));
}

__device__ __forceinline__ v4f silu4(v4f v) {
    v4f r;
    r.x = silu1(v.x);
    r.y = silu1(v.y);
    r.z = silu1(v.z);
    r.w = silu1(v.w);
    return r;
}

__global__ __launch_bounds__(256) void shortconv_silu_kernel(
    const v4f* __restrict__ x4,   // (B, L, D/4)
    const float* __restrict__ w,  // (D, 1, K) flat = d*K + k
    v4f* __restrict__ o4)         // (B, L, D/4)
{
    const int col = blockIdx.x * blockDim.x + threadIdx.x;  // [0, COLS)
    const int l0  = blockIdx.y * LSTRIP;
    const int b   = blockIdx.z;
    const int d0  = col * 4;

    // Load weights (contiguous 16B per d), transpose so wk{k}[i] = w[d0+i][k].
    const v4f wrow0 = *reinterpret_cast<const v4f*>(w + (size_t)(d0 + 0) * KW);
    const v4f wrow1 = *reinterpret_cast<const v4f*>(w + (size_t)(d0 + 1) * KW);
    const v4f wrow2 = *reinterpret_cast<const v4f*>(w + (size_t)(d0 + 2) * KW);
    const v4f wrow3 = *reinterpret_cast<const v4f*>(w + (size_t)(d0 + 3) * KW);
    v4f wk0, wk1, wk2, wk3;
    wk0.x = wrow0.x; wk0.y = wrow1.x; wk0.z = wrow2.x; wk0.w = wrow3.x;
    wk1.x = wrow0.y; wk1.y = wrow1.y; wk1.z = wrow2.y; wk1.w = wrow3.y;
    wk2.x = wrow0.z; wk2.y = wrow1.z; wk2.z = wrow2.z; wk2.w = wrow3.z;
    wk3.x = wrow0.w; wk3.y = wrow1.w; wk3.z = wrow2.w; wk3.w = wrow3.w;

    const size_t base = (size_t)b * LEN * COLS + col;
    const v4f zero = {0.f, 0.f, 0.f, 0.f};

    // Sliding window registers: win0 = x[l-3], win1 = x[l-2], win2 = x[l-1]
    v4f win0 = (l0 - 3 >= 0) ? x4[base + (size_t)(l0 - 3) * COLS] : zero;
    v4f win1 = (l0 - 2 >= 0) ? x4[base + (size_t)(l0 - 2) * COLS] : zero;
    v4f win2 = (l0 - 1 >= 0) ? x4[base + (size_t)(l0 - 1) * COLS] : zero;

    #pragma unroll
    for (int g = 0; g < LSTRIP / 4; ++g) {
        const size_t p = base + (size_t)(l0 + g * 4) * COLS;
        // Batch 4 independent loads -> 4 outstanding 1KB wave-loads.
        const v4f xc0 = x4[p + 0 * COLS];
        const v4f xc1 = x4[p + 1 * COLS];
        const v4f xc2 = x4[p + 2 * COLS];
        const v4f xc3 = x4[p + 3 * COLS];

        v4f y0 = wk0 * win0 + wk1 * win1 + wk2 * win2 + wk3 * xc0;
        v4f y1 = wk0 * win1 + wk1 * win2 + wk2 * xc0  + wk3 * xc1;
        v4f y2 = wk0 * win2 + wk1 * xc0  + wk2 * xc1  + wk3 * xc2;
        v4f y3 = wk0 * xc0  + wk1 * xc1  + wk2 * xc2  + wk3 * xc3;

        y0 = silu4(y0);
        y1 = silu4(y1);
        y2 = silu4(y2);
        y3 = silu4(y3);

        // Non-temporal: output never re-read by this kernel.
        __builtin_nontemporal_store(y0, o4 + p + 0 * COLS);
        __builtin_nontemporal_store(y1, o4 + p + 1 * COLS);
        __builtin_nontemporal_store(y2, o4 + p + 2 * COLS);
        __builtin_nontemporal_store(y3, o4 + p + 3 * COLS);

        win0 = xc1; win1 = xc2; win2 = xc3;
    }
}

extern "C" void kernel_launch(void* const* d_in, const int* in_sizes, int n_in,
                              void* d_out, int out_size, void* d_ws, size_t ws_size,
                              hipStream_t stream) {
    const v4f* x4 = (const v4f*)d_in[0];
    const float* w = (const float*)d_in[1];
    v4f* o4 = (v4f*)d_out;

    dim3 block(256, 1, 1);
    dim3 grid(COLS / 256, LEN / LSTRIP, NB);  // (2, 256, 4) = 2048 blocks
    shortconv_silu_kernel<<<grid, block, 0, stream>>>(x4, w, o4);
}

// Round 4
// 47.295 us; speedup vs baseline: 1.0851x; 1.0140x over previous
//
#include <hip/hip_runtime.h>

#define DIM 2048
#define LEN 4096
#define NB  4
#define KW  4
#define LSTRIP 32
#define COLS (DIM / 4)   // 512 float4 columns

typedef float v4f __attribute__((ext_vector_type(4)));

__device__ __forceinline__ float silu1(float v) {
    // v * sigmoid(v); rcp approx ~1ulp, far inside 7.75e-2 threshold.
    return v * __builtin_amdgcn_rcpf(1.f + __expf(-v));
}

__device__ __forceinline__ v4f silu4(v4f v) {
    v4f r;
    r.x = silu1(v.x);
    r.y = silu1(v.y);
    r.z = silu1(v.z);
    r.w = silu1(v.w);
    return r;
}

// One block = one full (B-slice) row range: 512 threads cover all 512 float4
// columns, LSTRIP=32 consecutive rows -> contiguous 256KB read span and
// contiguous 256KB write span per block (long DRAM streams, 9% halo).
__global__ __launch_bounds__(512) void shortconv_silu_kernel(
    const v4f* __restrict__ x4,   // (B, L, D/4)
    const float* __restrict__ w,  // (D, 1, K) flat = d*K + k
    v4f* __restrict__ o4)         // (B, L, D/4)
{
    const int col = threadIdx.x;            // [0, 512)
    const int l0  = blockIdx.x * LSTRIP;
    const int b   = blockIdx.y;
    const int d0  = col * 4;

    // Weights: contiguous 16B per d, transpose so wk{k}[i] = w[d0+i][k].
    const v4f wrow0 = *reinterpret_cast<const v4f*>(w + (size_t)(d0 + 0) * KW);
    const v4f wrow1 = *reinterpret_cast<const v4f*>(w + (size_t)(d0 + 1) * KW);
    const v4f wrow2 = *reinterpret_cast<const v4f*>(w + (size_t)(d0 + 2) * KW);
    const v4f wrow3 = *reinterpret_cast<const v4f*>(w + (size_t)(d0 + 3) * KW);
    v4f wk0, wk1, wk2, wk3;
    wk0.x = wrow0.x; wk0.y = wrow1.x; wk0.z = wrow2.x; wk0.w = wrow3.x;
    wk1.x = wrow0.y; wk1.y = wrow1.y; wk1.z = wrow2.y; wk1.w = wrow3.y;
    wk2.x = wrow0.z; wk2.y = wrow1.z; wk2.z = wrow2.z; wk2.w = wrow3.z;
    wk3.x = wrow0.w; wk3.y = wrow1.w; wk3.z = wrow2.w; wk3.w = wrow3.w;

    const size_t base = (size_t)b * LEN * COLS + col;
    const v4f zero = {0.f, 0.f, 0.f, 0.f};

    // Sliding window: win0 = x[l-3], win1 = x[l-2], win2 = x[l-1]
    v4f win0 = (l0 - 3 >= 0) ? x4[base + (size_t)(l0 - 3) * COLS] : zero;
    v4f win1 = (l0 - 2 >= 0) ? x4[base + (size_t)(l0 - 2) * COLS] : zero;
    v4f win2 = (l0 - 1 >= 0) ? x4[base + (size_t)(l0 - 1) * COLS] : zero;

    #pragma unroll
    for (int g = 0; g < LSTRIP / 4; ++g) {
        const size_t p = base + (size_t)(l0 + g * 4) * COLS;
        // 4 independent 1KB wave-loads in flight.
        const v4f xc0 = x4[p + 0 * COLS];
        const v4f xc1 = x4[p + 1 * COLS];
        const v4f xc2 = x4[p + 2 * COLS];
        const v4f xc3 = x4[p + 3 * COLS];

        v4f y0 = wk0 * win0 + wk1 * win1 + wk2 * win2 + wk3 * xc0;
        v4f y1 = wk0 * win1 + wk1 * win2 + wk2 * xc0  + wk3 * xc1;
        v4f y2 = wk0 * win2 + wk1 * xc0  + wk2 * xc1  + wk3 * xc2;
        v4f y3 = wk0 * xc0  + wk1 * xc1  + wk2 * xc2  + wk3 * xc3;

        y0 = silu4(y0);
        y1 = silu4(y1);
        y2 = silu4(y2);
        y3 = silu4(y3);

        __builtin_nontemporal_store(y0, o4 + p + 0 * COLS);
        __builtin_nontemporal_store(y1, o4 + p + 1 * COLS);
        __builtin_nontemporal_store(y2, o4 + p + 2 * COLS);
        __builtin_nontemporal_store(y3, o4 + p + 3 * COLS);

        win0 = xc1; win1 = xc2; win2 = xc3;
    }
}

extern "C" void kernel_launch(void* const* d_in, const int* in_sizes, int n_in,
                              void* d_out, int out_size, void* d_ws, size_t ws_size,
                              hipStream_t stream) {
    const v4f* x4 = (const v4f*)d_in[0];
    const float* w = (const float*)d_in[1];
    v4f* o4 = (v4f*)d_out;

    dim3 block(512, 1, 1);
    dim3 grid(LEN / LSTRIP, NB, 1);  // (128, 4) = 512 blocks, 8 waves each
    shortconv_silu_kernel<<<grid, block, 0, stream>>>(x4, w, o4);
}